// Round 9
// baseline (332.255 us; speedup 1.0000x reference)
//
#include <hip/hip_runtime.h>
#include <hip/hip_bf16.h>

#define NN 100000
#define NE 1600000
#define D  128
#define NPAD 100352           // 392 * 256 = 196 * 512
#define NBLK 782              // ceil(NN / 128)
#define CAP  64               // max in-degree bucket (Poisson(16): P(>=64)~8e-20)

// coarse partition params
#define BSH    9              // bucket = dest >> 9  (512 nodes/bucket)
#define NB_C   196            // NPAD >> 9
#define CAPB   9216           // bucket arena capacity (mean 8163, +11 sigma)
#define PCHUNK 2048           // edges per partition block
#define PEPT   8              // edges per thread
#define NPART  782            // ceil(NE / PCHUNK)

// k_agg slice params
#define AGG_BLOCKS 2048       // fully-resident: 8 blocks/CU -> stable blk&7 -> XCD map
#define DESTS_PER_ROUND 1024  // (AGG_BLOCKS/8 slices) * 4 waves

typedef __attribute__((ext_vector_type(8))) short short8;
typedef __attribute__((ext_vector_type(4))) float floatx4;
typedef __attribute__((ext_vector_type(2))) float fx2;

__device__ __forceinline__ unsigned short f2b(float f) {
    __hip_bfloat16 h = __float2bfloat16(f);   // RNE
    return *(unsigned short*)&h;
}

// LDS tile swizzle for [128 rows][128 bf16] (256 B rows): XOR 16 B-granule
// index with (row&7) -- G4 pattern. In ushort units: col ^ ((row&7)<<3).
__device__ __forceinline__ int swz(int row, int col_us) {
    return row * 128 + (col_us ^ ((row & 7) << 3));
}

// -------------------------------------- coarse partition (196 buckets) ----
__global__ __launch_bounds__(256) void k_part(const int* __restrict__ row,
                                              const int* __restrict__ col,
                                              int* __restrict__ bcnt,
                                              unsigned int* __restrict__ edgesP) {
    __shared__ int cur[NB_C], basep[NB_C];
    int t = threadIdx.x;
    size_t e0 = (size_t)blockIdx.x * PCHUNK;

    for (int i = t; i < NB_C; i += 256) cur[i] = 0;
    __syncthreads();

    unsigned int val[PEPT];
    int bk[PEPT], rk[PEPT];
#pragma unroll
    for (int i = 0; i < PEPT; ++i) {
        size_t e = e0 + i * 256 + t;
        bk[i] = -1;
        if (e < NE) {
            int r = row[e], c = col[e];
            if (r != c) {                      // existing self-loops weight 0
                bk[i]  = c >> BSH;
                val[i] = (unsigned)r | ((unsigned)(c & 511) << 17);
                rk[i]  = atomicAdd(&cur[bk[i]], 1);   // LDS atomic
            }
        }
    }
    __syncthreads();

    for (int i = t; i < NB_C; i += 256)
        basep[i] = cur[i] ? atomicAdd(&bcnt[i], cur[i]) : 0;
    __syncthreads();

#pragma unroll
    for (int i = 0; i < PEPT; ++i) {
        if (bk[i] >= 0) {
            int pos = basep[bk[i]] + rk[i];
            if (pos < CAPB) edgesP[(size_t)bk[i] * CAPB + pos] = val[i];
        }
    }
}

// ------------------------------------------ fine fill (1 block/bucket) ----
__global__ __launch_bounds__(1024) void k_fine(const int* __restrict__ bcnt,
                                               const unsigned int* __restrict__ edgesP,
                                               int* __restrict__ counts,
                                               float* __restrict__ dinv,
                                               int* __restrict__ srcs) {
    __shared__ int cnt[512];
    int t = threadIdx.x, b = blockIdx.x;
    int n0 = b << BSH;
    for (int i = t; i < 512; i += 1024) cnt[i] = 0;
    __syncthreads();

    int m = min(bcnt[b], CAPB);
    const unsigned int* ep = edgesP + (size_t)b * CAPB;
    for (int i = t; i < m; i += 1024) {
        unsigned int v = ep[i];
        int c0 = v >> 17;                     // dest & 511
        int s  = v & 0x1FFFF;                 // src
        int pos = atomicAdd(&cnt[c0], 1);     // LDS atomic
        if (pos < CAP) srcs[(size_t)(n0 + c0) * CAP + pos] = s;
    }
    __syncthreads();
    for (int i = t; i < 512; i += 1024) {
        int n = n0 + i;
        int cv = cnt[i];
        counts[n] = min(cv, CAP);
        dinv[n] = rsqrtf((float)cv + 1.0f);   // +1 appended self-loop (true degree)
    }
}

// --------------------------------------------- W^T convert (fp32 -> bf16) ----
// Writes wt in the SWIZZLED layout so k_gemm's linear LDS copy + swizzled
// fragment reads are consistent.
__global__ void k_prep_w(const float* __restrict__ w, unsigned short* __restrict__ wt) {
    int i = blockIdx.x * 256 + threadIdx.x;   // over 128*128
    int n = i >> 7, k = i & 127;
    wt[swz(n, k)] = f2b(w[k * D + n]);
}

// --------------------------------- bf16 MFMA GEMM: yw = bf16(dinv .* (x W)) ----
// 128x128 block tile, 4 waves in 64x64 quadrants, mfma_f32_16x16x32_bf16.
// Both LDS tiles XOR-swizzled (r5 win). Epilogue stages C into the dead sX
// buffer (r7, neutral but correct) -- now flushed in SLICE-MAJOR layout
// yw[slice][node][16 bf16]: each 3.2 MB slice is contiguous -> fits one
// XCD's 4 MB L2 for the sliced k_agg. Flush: lane covers one (slice,row)
// 32 B run -> fully coalesced 2 KB/wave-instr pair.
__global__ __launch_bounds__(256, 2) void k_gemm_mfma(const float* __restrict__ x,
                                                      const unsigned short* __restrict__ wt,
                                                      const float* __restrict__ dinv,
                                                      unsigned short* __restrict__ yw) {
    __shared__ unsigned short sX[128 * 128];   // 32 KB bf16 x-tile (swizzled); reused for C
    __shared__ unsigned short sW[128 * 128];   // 32 KB bf16 W^T (swizzled)
    __shared__ float sD[128];
    int tid = threadIdx.x;
    long row0 = (long)blockIdx.x * 128;

    if (tid < 128) {
        long gr = row0 + tid;
        sD[tid] = (gr < NN) ? dinv[gr] : 0.0f;
    }
    {
        const uint4* src = (const uint4*)wt;
        uint4* dst = (uint4*)sW;
#pragma unroll
        for (int j = 0; j < 8; ++j) dst[tid + j * 256] = src[tid + j * 256];
    }
#pragma unroll
    for (int j = 0; j < 16; ++j) {
        int i = tid + j * 256;
        int r = i >> 5, q = i & 31;            // row r, 8 B chunk q (4 ushorts)
        floatx4 v = {0.f, 0.f, 0.f, 0.f};
        long gr = row0 + r;
        if (gr < NN) v = __builtin_nontemporal_load((const floatx4*)(x + gr * D + q * 4));
        ushort4 u;
        u.x = f2b(v.x); u.y = f2b(v.y); u.z = f2b(v.z); u.w = f2b(v.w);
        *(ushort4*)&sX[swz(r, q * 4)] = u;
    }
    __syncthreads();

    int lane = tid & 63, wave = tid >> 6;
    int wm = (wave & 1) * 64, wn = (wave >> 1) * 64;
    int lrow = lane & 15, lkb = (lane >> 4) * 8;

    floatx4 acc[4][4] = {};
#pragma unroll
    for (int kc = 0; kc < 4; ++kc) {
        int kb = kc * 32 + lkb;
        short8 bfr[4];
#pragma unroll
        for (int tn = 0; tn < 4; ++tn)
            bfr[tn] = *(const short8*)&sW[swz(wn + tn * 16 + lrow, kb)];
#pragma unroll
        for (int tm = 0; tm < 4; ++tm) {
            short8 afr = *(const short8*)&sX[swz(wm + tm * 16 + lrow, kb)];
#pragma unroll
            for (int tn = 0; tn < 4; ++tn)
                acc[tm][tn] = __builtin_amdgcn_mfma_f32_16x16x32_bf16(afr, bfr[tn], acc[tm][tn], 0, 0, 0);
        }
    }

    // ---- epilogue: stage C into sX (swizzled), flush slice-major ----
    __syncthreads();                           // all waves done reading sX/sW

    int orow = (lane >> 4) * 4;
    int ocol = lane & 15;
#pragma unroll
    for (int tm = 0; tm < 4; ++tm) {
#pragma unroll
        for (int reg = 0; reg < 4; ++reg) {
            int rt = wm + tm * 16 + orow + reg;
            float dm = sD[rt];
#pragma unroll
            for (int tn = 0; tn < 4; ++tn)
                sX[swz(rt, wn + tn * 16 + ocol)] = f2b(acc[tm][tn][reg] * dm);
        }
    }
    __syncthreads();

    // flush: 1024 tasks; task i = (row r = i&127, slice sl8 = i>>7), 32 B each
#pragma unroll
    for (int j = 0; j < 4; ++j) {
        int i = tid + j * 256;
        int r = i & 127, sl8 = i >> 7;
        long gr = row0 + r;
        if (gr < NN) {
            uint4 v0 = *(const uint4*)&sX[swz(r, sl8 * 16)];
            uint4 v1 = *(const uint4*)&sX[swz(r, sl8 * 16 + 8)];
            unsigned short* dst = yw + ((size_t)sl8 * NN + gr) * 16;
            *(uint4*)dst = v0;
            *(uint4*)(dst + 8) = v1;
        }
    }
}

// --------------------------- per-node aggregate, XCD-sliced, barrier-free ----
// Evidence: r1/r3 (issue/latency not the wall), r6 (slicing cuts FETCH
// 190->66 MB = L2-miss path IS the wall, but barriers+32B/instr regressed).
// This version: slice-major yw, slice = blockIdx&7 rides the round-robin
// block->XCD map, fully-resident 2048-block grid (stable mapping, proven
// by r6's FETCH collapse). NO barriers, NO LDS: one wave owns one dest
// (r5's proven shape); 8 src-groups x 8 dword-lanes -> 8 srcs x 32 B per
// gather instr, 2 in flight; 3 shfl_xor rounds fold the groups; 8 lanes
// store 64 B contiguous. srcs plain loads (L3-cacheable across 8 passes).
__global__ __launch_bounds__(256, 8) void k_agg(const int* __restrict__ counts,
                                                const int* __restrict__ srcs,
                                                const float* __restrict__ dinv,
                                                const unsigned int* __restrict__ ywd,
                                                const float* __restrict__ bias,
                                                float* __restrict__ out) {
    int lane = threadIdx.x & 63;
    int wv = threadIdx.x >> 6;
    int sl = blockIdx.x & 7;                   // slice -> XCD (round-robin)
    int g = lane >> 3, j = lane & 7;           // src-group, col-dword

    const unsigned int* yws = ywd + (size_t)sl * NN * 8 + j;
    fx2 b2 = *(const fx2*)(bias + sl * 16 + 2 * j);

    for (int c = (blockIdx.x >> 3) * 4 + wv; c < NN; c += DESTS_PER_ROUND) {
        int cnt0 = min(counts[c], 63);
        const int* sp = srcs + (size_t)c * CAP;
        int mysrc = c;                         // lane 0 = self-loop source
        if (lane >= 1 && lane <= cnt0) mysrc = sp[lane - 1];
        int ec = cnt0 + 1;

        float a0 = 0.0f, a1 = 0.0f;
        for (int p = 0; p < ec; p += 16) {
            int i0 = p + g, i1 = p + 8 + g;
            int s0 = __shfl(mysrc, (i0 < ec) ? i0 : 0);
            int s1 = __shfl(mysrc, (i1 < ec) ? i1 : 0);
            unsigned int v0 = yws[(size_t)s0 * 8];
            unsigned int v1 = yws[(size_t)s1 * 8];
            if (i0 < ec) {
                a0 += __uint_as_float(v0 << 16);
                a1 += __uint_as_float(v0 & 0xFFFF0000u);
            }
            if (i1 < ec) {
                a0 += __uint_as_float(v1 << 16);
                a1 += __uint_as_float(v1 & 0xFFFF0000u);
            }
        }

        // fold the 8 src-groups: lanes with same j across g
        a0 += __shfl_xor(a0, 8);   a1 += __shfl_xor(a1, 8);
        a0 += __shfl_xor(a0, 16);  a1 += __shfl_xor(a1, 16);
        a0 += __shfl_xor(a0, 32);  a1 += __shfl_xor(a1, 32);

        if (g == 0) {                          // 8 lanes store 64 B contiguous
            float dc = dinv[c];
            fx2 o;
            o.x = dc * a0 + b2.x;
            o.y = dc * a1 + b2.y;
            __builtin_nontemporal_store(o, (fx2*)(out + (size_t)c * D + sl * 16 + 2 * j));
        }
    }
}

// ---------------------------------------------------------------- launch ----
extern "C" void kernel_launch(void* const* d_in, const int* in_sizes, int n_in,
                              void* d_out, int out_size, void* d_ws, size_t ws_size,
                              hipStream_t stream) {
    const float* x    = (const float*)d_in[0];
    const int*   ei   = (const int*)d_in[1];      // [2, NE] (int32 on device)
    const float* w    = (const float*)d_in[2];
    const float* bias = (const float*)d_in[3];
    float*       out  = (float*)d_out;

    const int* row = ei;
    const int* col = ei + NE;

    // ws layout (~52 MB, 16B-aligned segments):
    int*   counts = (int*)d_ws;                          // NPAD
    float* dinv   = (float*)(counts + NPAD);             // NPAD
    int*   srcs   = (int*)(dinv + NPAD);                 // NN*CAP   (25.6 MB)
    unsigned short* yw = (unsigned short*)(srcs + (size_t)NN * CAP);  // NN*D bf16, slice-major
    unsigned short* wt = yw + (size_t)NN * D;            // 128*128 bf16
    int*   bcnt   = (int*)(wt + 128 * 128);              // NB_C
    // edgesP (196*9216 u32 = 7.2 MB) aliases yw: dead before k_gemm_mfma runs
    unsigned int* edgesP = (unsigned int*)yw;

    hipMemsetAsync(bcnt, 0, NB_C * sizeof(int), stream);

    k_prep_w<<<64, 256, 0, stream>>>(w, wt);
    k_part<<<NPART, 256, 0, stream>>>(row, col, bcnt, edgesP);
    k_fine<<<NB_C, 1024, 0, stream>>>(bcnt, edgesP, counts, dinv, srcs);
    k_gemm_mfma<<<NBLK, 256, 0, stream>>>(x, wt, dinv, yw);
    k_agg<<<AGG_BLOCKS, 256, 0, stream>>>(counts, srcs, dinv, (const unsigned int*)yw, bias, out);
}

// Round 10
// 223.055 us; speedup vs baseline: 1.4896x; 1.4896x over previous
//
#include <hip/hip_runtime.h>
#include <hip/hip_bf16.h>

#define NN 100000
#define NE 1600000
#define D  128
#define NPAD 100352           // 392 * 256 = 196 * 512
#define NBLK 782              // ceil(NN / 128)
#define CAP  64               // max in-degree bucket (Poisson(16): P(>=64)~8e-20)

// coarse partition params
#define BSH    9              // bucket = dest >> 9  (512 nodes/bucket)
#define NB_C   196            // NPAD >> 9
#define CAPB   9216           // bucket arena capacity (mean 8163, +11 sigma)
#define PCHUNK 8192           // edges per partition block (r10: was 2048)
#define PEPT   8              // edges per thread (1024 threads)
#define NPART  196            // ceil(NE / PCHUNK)

typedef __attribute__((ext_vector_type(8))) short short8;
typedef __attribute__((ext_vector_type(4))) float floatx4;
typedef __attribute__((ext_vector_type(4))) unsigned int uintx4;

__device__ __forceinline__ unsigned short f2b(float f) {
    __hip_bfloat16 h = __float2bfloat16(f);   // RNE
    return *(unsigned short*)&h;
}

// unpack one uintx4 (8 bf16) and accumulate into 8 fp32 lane-local slots
__device__ __forceinline__ void acc8(float (&a)[8], uintx4 v) {
    a[0] += __uint_as_float(v.x << 16);
    a[1] += __uint_as_float(v.x & 0xFFFF0000u);
    a[2] += __uint_as_float(v.y << 16);
    a[3] += __uint_as_float(v.y & 0xFFFF0000u);
    a[4] += __uint_as_float(v.z << 16);
    a[5] += __uint_as_float(v.z & 0xFFFF0000u);
    a[6] += __uint_as_float(v.w << 16);
    a[7] += __uint_as_float(v.w & 0xFFFF0000u);
}

// LDS tile swizzle for [128 rows][128 bf16] (256 B rows): XOR 16 B-granule
// index with (row&7) -- G4 pattern. In ushort units: col ^ ((row&7)<<3).
__device__ __forceinline__ int swz(int row, int col_us) {
    return row * 128 + (col_us ^ ((row & 7) << 3));
}

// -------------------------------------- coarse partition (196 buckets) ----
// r10: 8192 edges/block @ 1024 threads (was 2048 @ 256): bucket write runs
// grow 42 B -> 168 B (line-coalesced), 4x fewer global-atomic rounds.
__global__ __launch_bounds__(1024) void k_part(const int* __restrict__ row,
                                               const int* __restrict__ col,
                                               int* __restrict__ bcnt,
                                               unsigned int* __restrict__ edgesP) {
    __shared__ int cur[NB_C], basep[NB_C];
    int t = threadIdx.x;
    size_t e0 = (size_t)blockIdx.x * PCHUNK;

    for (int i = t; i < NB_C; i += 1024) cur[i] = 0;
    __syncthreads();

    unsigned int val[PEPT];
    int bk[PEPT], rk[PEPT];
#pragma unroll
    for (int i = 0; i < PEPT; ++i) {
        size_t e = e0 + i * 1024 + t;
        bk[i] = -1;
        if (e < NE) {
            int r = row[e], c = col[e];
            if (r != c) {                      // existing self-loops weight 0
                bk[i]  = c >> BSH;
                val[i] = (unsigned)r | ((unsigned)(c & 511) << 17);
                rk[i]  = atomicAdd(&cur[bk[i]], 1);   // LDS atomic
            }
        }
    }
    __syncthreads();

    for (int i = t; i < NB_C; i += 1024)
        basep[i] = cur[i] ? atomicAdd(&bcnt[i], cur[i]) : 0;
    __syncthreads();

#pragma unroll
    for (int i = 0; i < PEPT; ++i) {
        if (bk[i] >= 0) {
            int pos = basep[bk[i]] + rk[i];
            if (pos < CAPB) edgesP[(size_t)bk[i] * CAPB + pos] = val[i];
        }
    }
}

// ------------------------------------------ fine fill (1 block/bucket) ----
__global__ __launch_bounds__(1024) void k_fine(const int* __restrict__ bcnt,
                                               const unsigned int* __restrict__ edgesP,
                                               int* __restrict__ counts,
                                               float* __restrict__ dinv,
                                               int* __restrict__ srcs) {
    __shared__ int cnt[512];
    int t = threadIdx.x, b = blockIdx.x;
    int n0 = b << BSH;
    for (int i = t; i < 512; i += 1024) cnt[i] = 0;
    __syncthreads();

    int m = min(bcnt[b], CAPB);
    const unsigned int* ep = edgesP + (size_t)b * CAPB;
    for (int i = t; i < m; i += 1024) {
        unsigned int v = ep[i];
        int c0 = v >> 17;                     // dest & 511
        int s  = v & 0x1FFFF;                 // src
        int pos = atomicAdd(&cnt[c0], 1);     // LDS atomic
        if (pos < CAP) srcs[(size_t)(n0 + c0) * CAP + pos] = s;
    }
    __syncthreads();
    for (int i = t; i < 512; i += 1024) {
        int n = n0 + i;
        int cv = cnt[i];
        counts[n] = min(cv, CAP);
        dinv[n] = rsqrtf((float)cv + 1.0f);   // +1 appended self-loop (true degree)
    }
}

// --------------------------------- bf16 MFMA GEMM: yw = bf16(dinv .* (x W)) ----
// 128x128 block tile, 4 waves in 64x64 quadrants, mfma_f32_16x16x32_bf16.
// Both LDS tiles XOR-swizzled (r5 win). r10: W fp32->bf16(swizzled) staged
// IN-KERNEL (k_prep_w launch deleted; W is 64 KB, L2-cached across blocks).
// Epilogue stages C into the dead sX buffer, flushes row-major coalesced.
__global__ __launch_bounds__(256, 2) void k_gemm_mfma(const float* __restrict__ x,
                                                      const float* __restrict__ w,
                                                      const float* __restrict__ dinv,
                                                      unsigned short* __restrict__ yw) {
    __shared__ unsigned short sX[128 * 128];   // 32 KB bf16 x-tile (swizzled); reused for C
    __shared__ unsigned short sW[128 * 128];   // 32 KB bf16 W^T (swizzled)
    __shared__ float sD[128];
    int tid = threadIdx.x;
    long row0 = (long)blockIdx.x * 128;

    if (tid < 128) {
        long gr = row0 + tid;
        sD[tid] = (gr < NN) ? dinv[gr] : 0.0f;
    }
    // stage W: w[k*128+n] fp32 -> sW[swz(n,k)] bf16 (W^T, swizzled)
#pragma unroll
    for (int j = 0; j < 16; ++j) {
        int i4 = tid + j * 256;                // float4 index, 0..4095
        int i = i4 * 4;
        int k = i >> 7, n = i & 127;           // 4 consecutive n, same k
        floatx4 v = *(const floatx4*)(w + i);
        sW[swz(n + 0, k)] = f2b(v.x);
        sW[swz(n + 1, k)] = f2b(v.y);
        sW[swz(n + 2, k)] = f2b(v.z);
        sW[swz(n + 3, k)] = f2b(v.w);
    }
#pragma unroll
    for (int j = 0; j < 16; ++j) {
        int i = tid + j * 256;
        int r = i >> 5, q = i & 31;            // row r, 8 B chunk q (4 ushorts)
        floatx4 v = {0.f, 0.f, 0.f, 0.f};
        long gr = row0 + r;
        if (gr < NN) v = __builtin_nontemporal_load((const floatx4*)(x + gr * D + q * 4));
        ushort4 u;
        u.x = f2b(v.x); u.y = f2b(v.y); u.z = f2b(v.z); u.w = f2b(v.w);
        *(ushort4*)&sX[swz(r, q * 4)] = u;
    }
    __syncthreads();

    int lane = tid & 63, wave = tid >> 6;
    int wm = (wave & 1) * 64, wn = (wave >> 1) * 64;
    int lrow = lane & 15, lkb = (lane >> 4) * 8;

    floatx4 acc[4][4] = {};
#pragma unroll
    for (int kc = 0; kc < 4; ++kc) {
        int kb = kc * 32 + lkb;
        short8 bfr[4];
#pragma unroll
        for (int tn = 0; tn < 4; ++tn)
            bfr[tn] = *(const short8*)&sW[swz(wn + tn * 16 + lrow, kb)];
#pragma unroll
        for (int tm = 0; tm < 4; ++tm) {
            short8 afr = *(const short8*)&sX[swz(wm + tm * 16 + lrow, kb)];
#pragma unroll
            for (int tn = 0; tn < 4; ++tn)
                acc[tm][tn] = __builtin_amdgcn_mfma_f32_16x16x32_bf16(afr, bfr[tn], acc[tm][tn], 0, 0, 0);
        }
    }

    // ---- epilogue: stage C into sX (swizzled), flush row-major coalesced ----
    __syncthreads();                           // all waves done reading sX/sW

    int orow = (lane >> 4) * 4;
    int ocol = lane & 15;
#pragma unroll
    for (int tm = 0; tm < 4; ++tm) {
#pragma unroll
        for (int reg = 0; reg < 4; ++reg) {
            int rt = wm + tm * 16 + orow + reg;
            float dm = sD[rt];
#pragma unroll
            for (int tn = 0; tn < 4; ++tn)
                sX[swz(rt, wn + tn * 16 + ocol)] = f2b(acc[tm][tn][reg] * dm);
        }
    }
    __syncthreads();

    // flush: 2048 granules of 16 B; thread i covers granule (r = i>>4, cg = i&15)
#pragma unroll
    for (int j = 0; j < 8; ++j) {
        int i = tid + j * 256;
        int r = i >> 4, cg = i & 15;
        long gr = row0 + r;
        if (gr < NN) {
            uint4 v = *(const uint4*)&sX[swz(r, cg * 8)];
            *(uint4*)(yw + gr * D + cg * 8) = v;
        }
    }
}

// --------------------------------------- per-node aggregate, wave/dest ----
// r5 champion (restored, permanent): dwordx4 gather -- each wave-instr moves
// FOUR 256 B yw rows (lane group g=lane>>4 owns source p+g; lane f=lane&15
// holds a 16 B row slice). ~3.9 TB/s mixed-fabric is the structural limit
// for this random-256B pattern: r1 (MLP depth), r3 (4x fewer instrs), r6/r9
// (XCD-sliced: FETCH 190->66-79 MB confirmed locality, but 8x per-dest
// overhead + 4 B/lane gathers tripled time) all failed to beat it.
__global__ __launch_bounds__(256) void k_agg(const int* __restrict__ counts,
                                             const int* __restrict__ srcs,
                                             const float* __restrict__ dinv,
                                             const uintx4* __restrict__ yw4,
                                             const float* __restrict__ bias,
                                             float* __restrict__ out) {
    int lane = threadIdx.x & 63;
    int c = blockIdx.x * 4 + (threadIdx.x >> 6);
    int g = lane >> 4, f = lane & 15;

    // effective source list: [c (self), srcs[0..cnt0-1]], cnt0 capped at 63
    int cnt0 = min(counts[c], 63);
    const int* sp = srcs + (size_t)c * CAP;
    int mysrc = c;
    if (lane >= 1 && lane <= cnt0) mysrc = __builtin_nontemporal_load(sp + lane - 1);
    int ec = cnt0 + 1;

    float dc = dinv[c];

    float a[8] = {0.f, 0.f, 0.f, 0.f, 0.f, 0.f, 0.f, 0.f};

    int p = 0;
    for (; p + 16 <= ec; p += 16) {
        uintx4 v[4];
#pragma unroll
        for (int i = 0; i < 4; ++i) {
            int s = __shfl(mysrc, p + i * 4 + g);
            v[i] = yw4[(size_t)s * 16 + f];
        }
#pragma unroll
        for (int i = 0; i < 4; ++i) acc8(a, v[i]);
    }
    if (p + 8 <= ec) {
        uintx4 v[2];
#pragma unroll
        for (int i = 0; i < 2; ++i) {
            int s = __shfl(mysrc, p + i * 4 + g);
            v[i] = yw4[(size_t)s * 16 + f];
        }
#pragma unroll
        for (int i = 0; i < 2; ++i) acc8(a, v[i]);
        p += 8;
    }
    if (p + 4 <= ec) {
        int s = __shfl(mysrc, p + g);
        uintx4 v = yw4[(size_t)s * 16 + f];
        acc8(a, v);
        p += 4;
    }
    int r = ec - p;                            // 0..3 remaining
    if (r > 0) {
        int s = __shfl(mysrc, p + ((g < r) ? g : 0));
        uintx4 v = yw4[(size_t)s * 16 + f];
        if (g < r) acc8(a, v);
    }

    // combine the 4 group-partials: lanes {f, f+16, f+32, f+48} -> full sum
#pragma unroll
    for (int j = 0; j < 8; ++j) a[j] += __shfl_xor(a[j], 16);
#pragma unroll
    for (int j = 0; j < 8; ++j) a[j] += __shfl_xor(a[j], 32);

    if (g == 0) {                              // lanes 0-15 store the row
        const floatx4* b4 = (const floatx4*)bias;
        floatx4 b0 = b4[f * 2], b1 = b4[f * 2 + 1];
        floatx4 o0, o1;
        o0.x = dc * a[0] + b0.x;  o0.y = dc * a[1] + b0.y;
        o0.z = dc * a[2] + b0.z;  o0.w = dc * a[3] + b0.w;
        o1.x = dc * a[4] + b1.x;  o1.y = dc * a[5] + b1.y;
        o1.z = dc * a[6] + b1.z;  o1.w = dc * a[7] + b1.w;
        floatx4* op = (floatx4*)(out + (size_t)c * D + f * 8);
        __builtin_nontemporal_store(o0, op);
        __builtin_nontemporal_store(o1, op + 1);
    }
}

// ---------------------------------------------------------------- launch ----
extern "C" void kernel_launch(void* const* d_in, const int* in_sizes, int n_in,
                              void* d_out, int out_size, void* d_ws, size_t ws_size,
                              hipStream_t stream) {
    const float* x    = (const float*)d_in[0];
    const int*   ei   = (const int*)d_in[1];      // [2, NE] (int32 on device)
    const float* w    = (const float*)d_in[2];
    const float* bias = (const float*)d_in[3];
    float*       out  = (float*)d_out;

    const int* row = ei;
    const int* col = ei + NE;

    // ws layout (~52 MB, 16B-aligned segments):
    int*   counts = (int*)d_ws;                          // NPAD
    float* dinv   = (float*)(counts + NPAD);             // NPAD
    int*   srcs   = (int*)(dinv + NPAD);                 // NN*CAP   (25.6 MB)
    unsigned short* yw = (unsigned short*)(srcs + (size_t)NN * CAP);  // NN*D bf16 (25.6 MB)
    int*   bcnt   = (int*)(yw + (size_t)NN * D);         // NB_C
    // edgesP (196*9216 u32 = 7.2 MB) aliases yw: dead before k_gemm_mfma runs
    unsigned int* edgesP = (unsigned int*)yw;

    hipMemsetAsync(bcnt, 0, NB_C * sizeof(int), stream);

    k_part<<<NPART, 1024, 0, stream>>>(row, col, bcnt, edgesP);
    k_fine<<<NB_C, 1024, 0, stream>>>(bcnt, edgesP, counts, dinv, srcs);
    k_gemm_mfma<<<NBLK, 256, 0, stream>>>(x, w, dinv, yw);
    k_agg<<<NN / 4, 256, 0, stream>>>(counts, srcs, dinv, (const uintx4*)yw, bias, out);
}